// Round 11
// baseline (129.768 us; speedup 1.0000x reference)
//
#include <hip/hip_runtime.h>

// Speech MSA with dynamic windows.
// B=4, T=4160 (W=64 word tokens + F=4096 frames), E=256, H=4, D=64,
// LOCAL_SIZE=15 (pad 7), chunk = F/W = 64, n = B*H = 16.
//
// R11: 3 dispatches (was 4). conv folded into the qkv launch as extra blocks:
// qkv gemm blocks (0..767) load fp32 Wq directly with inline f16 convert
// (same rounding as the pre-converted WqT -> bit-identical), conv blocks
// (768..1283) produce WoT/wmT/xT for the downstream kernels. attn and out
// are byte-identical to R10 (passed at absmax 0.0078125).

#define QN 4194304ull  // 16 * 4096 * 64 elements (head-layout buffers)

typedef _Float16 h8 __attribute__((ext_vector_type(8)));
typedef float f32x16 __attribute__((ext_vector_type(16)));

// ---------------------------------------------- K1: QKV gemm + conv blocks
// blocks [0,768):    gemm M=16384, N=768, K=256. 128x128 tile, 4 waves
//                    (each 64x64), BK=32 x 8 iters. A from fp32 x (inline
//                    cvt), B from fp32 Wq (inline cvt, L2-resident).
// blocks [768,1024):  WoT [256][256] f16
// blocks [1024,1280): wmT [b][f][w] f16 (LDS 64x64 tile transpose)
// blocks [1280,1284): xT  [b][c][w] f16 (word-token rows transposed)
__global__ __launch_bounds__(256) void qkv_conv(
    const float* __restrict__ x, const float* __restrict__ wm,
    const float* __restrict__ Wq, const float* __restrict__ Wo,
    const float* __restrict__ bq,
    float* __restrict__ Qb, float* __restrict__ Kb, float* __restrict__ Vb,
    _Float16* __restrict__ woth, _Float16* __restrict__ wmth,
    _Float16* __restrict__ xth) {
  __shared__ union {
    struct { _Float16 Ah[128][40], Bh[128][40]; } g;  // 20480 B
    float S[64 * 65];                                  // 16640 B
  } sh;
  const int tid = threadIdx.x;
  const int u = blockIdx.x;

  if (u < 768) {
    // ---------------- gemm tile
    const int wave = tid >> 6, lane = tid & 63;
    const int ln = lane & 31, half = lane >> 5;
    const int mw = (wave & 1) * 64, nw = (wave >> 1) * 64;
    const int m0 = (u & 127) * 128, n0 = (u >> 7) * 128;

    const int sr = tid >> 1, scq = (tid & 1) * 16;
    const int am = m0 + sr;
    const size_t arow =
        ((size_t)((am >> 12) * 4160 + 64 + (am & 4095))) * 256 + scq;
    const int bn = n0 + sr;  // B row = output column n

    float4 rah0, rah1, rbh0, rbh1;
    auto QLOAD = [&](int k0_) {
      float4 fx0 = *(const float4*)(x + arow + k0_);
      float4 fx1 = *(const float4*)(x + arow + k0_ + 4);
      float4 fx2 = *(const float4*)(x + arow + k0_ + 8);
      float4 fx3 = *(const float4*)(x + arow + k0_ + 12);
      _Float16 hh[16] = {
          (_Float16)fx0.x, (_Float16)fx0.y, (_Float16)fx0.z, (_Float16)fx0.w,
          (_Float16)fx1.x, (_Float16)fx1.y, (_Float16)fx1.z, (_Float16)fx1.w,
          (_Float16)fx2.x, (_Float16)fx2.y, (_Float16)fx2.z, (_Float16)fx2.w,
          (_Float16)fx3.x, (_Float16)fx3.y, (_Float16)fx3.z, (_Float16)fx3.w};
      rah0 = *(float4*)&hh[0];
      rah1 = *(float4*)&hh[8];
      _Float16 bb[16];
#pragma unroll
      for (int j = 0; j < 16; ++j)
        bb[j] = (_Float16)Wq[(size_t)(k0_ + scq + j) * 768 + bn];
      rbh0 = *(float4*)&bb[0];
      rbh1 = *(float4*)&bb[8];
    };

    QLOAD(0);
    f32x16 acc[2][2] = {};

    for (int it = 0; it < 8; ++it) {
      __syncthreads();
      *(float4*)&sh.g.Ah[sr][scq] = rah0;
      *(float4*)&sh.g.Ah[sr][scq + 8] = rah1;
      *(float4*)&sh.g.Bh[sr][scq] = rbh0;
      *(float4*)&sh.g.Bh[sr][scq + 8] = rbh1;
      __syncthreads();
      if (it < 7) QLOAD((it + 1) * 32);
#pragma unroll
      for (int ks = 0; ks < 2; ++ks) {
        const int kc = ks * 16 + half * 8;
        h8 a0 = *(const h8*)&sh.g.Ah[mw + ln][kc];
        h8 a1 = *(const h8*)&sh.g.Ah[mw + 32 + ln][kc];
        h8 b0 = *(const h8*)&sh.g.Bh[nw + ln][kc];
        h8 b1 = *(const h8*)&sh.g.Bh[nw + 32 + ln][kc];
        acc[0][0] = __builtin_amdgcn_mfma_f32_32x32x16_f16(a0, b0, acc[0][0], 0, 0, 0);
        acc[0][1] = __builtin_amdgcn_mfma_f32_32x32x16_f16(a0, b1, acc[0][1], 0, 0, 0);
        acc[1][0] = __builtin_amdgcn_mfma_f32_32x32x16_f16(a1, b0, acc[1][0], 0, 0, 0);
        acc[1][1] = __builtin_amdgcn_mfma_f32_32x32x16_f16(a1, b1, acc[1][1], 0, 0, 0);
      }
    }

    // C/D: col = ln, row = (reg&3) + 8*(reg>>2) + 4*half
#pragma unroll
    for (int ni = 0; ni < 2; ++ni) {
      const int c = n0 + nw + ni * 32 + ln;
      const int which = c >> 8, e = c & 255;
      const int h = e >> 6, d = e & 63;
      float* dst = (which == 0) ? Qb : (which == 1) ? Kb : Vb;
      const float sc2 = (which == 0) ? 0.125f : 1.0f;
      const float bias = bq[c];
#pragma unroll
      for (int mi = 0; mi < 2; ++mi) {
        const int rb = m0 + mw + mi * 32 + 4 * half;
#pragma unroll
        for (int reg = 0; reg < 16; ++reg) {
          int rr = rb + (reg & 3) + 8 * (reg >> 2);
          int b2 = rr >> 12, f2 = rr & 4095;
          dst[(((size_t)(b2 * 4 + h)) * 4096 + f2) * 64 + d] =
              (acc[mi][ni][reg] + bias) * sc2;
        }
      }
    }
  } else if (u < 1024) {
    // ---------------- WoT [n][k] f16
    int o = (u - 768) * 256 + tid;
    int n = o >> 8, k = o & 255;
    woth[o] = (_Float16)Wo[(size_t)k * 256 + n];
  } else if (u < 1280) {
    // ---------------- wmT tile transpose
    int local = u - 1024;
    int b = local >> 6, f0 = (local & 63) * 64;
    {
      int w = tid >> 2, c0 = (tid & 3) * 16;
      const float* src = wm + ((size_t)(b * 64 + w)) * 4096 + f0 + c0;
#pragma unroll
      for (int cc = 0; cc < 16; cc += 4)
        *(float4*)&sh.S[w * 65 + c0 + cc] = *(const float4*)(src + cc);
    }
    __syncthreads();
    {
      int fl = tid >> 2, w0 = (tid & 3) * 16;
      int f = f0 + fl;
      _Float16 hh[16];
#pragma unroll
      for (int j = 0; j < 16; ++j) hh[j] = (_Float16)sh.S[(w0 + j) * 65 + fl];
      size_t o = ((size_t)b * 4096 + f) * 64 + w0;
      *(float4*)(wmth + o) = *(float4*)&hh[0];
      *(float4*)(wmth + o + 8) = *(float4*)&hh[8];
    }
  } else {
    // ---------------- xT: per b, 64 word tokens x 256 channels -> [c][w]
    int b = u - 1280;
    for (int c0 = 0; c0 < 256; c0 += 64) {
      __syncthreads();
      {
        int w = tid >> 2, cl0 = (tid & 3) * 16;
        const float* src = x + ((size_t)(b * 4160 + w)) * 256 + c0 + cl0;
#pragma unroll
        for (int cc = 0; cc < 16; cc += 4)
          *(float4*)&sh.S[w * 65 + cl0 + cc] = *(const float4*)(src + cc);
      }
      __syncthreads();
      {
        int cl = tid >> 2, w0 = (tid & 3) * 16;
        _Float16 hh[16];
#pragma unroll
        for (int j = 0; j < 16; ++j) hh[j] = (_Float16)sh.S[(w0 + j) * 65 + cl];
        size_t o = ((size_t)(b * 256 + c0 + cl)) * 64 + w0;
        *(float4*)(xth + o) = *(float4*)&hh[0];
        *(float4*)(xth + o + 8) = *(float4*)&hh[8];
      }
    }
  }
}

// ------------------------------------------------- K2: fused expa + attention
__global__ __launch_bounds__(256) void attn_fused(
    const float* __restrict__ Qb, const float* __restrict__ Kb,
    const float* __restrict__ Vb,
    const _Float16* __restrict__ wmth, const _Float16* __restrict__ xth,
    _Float16* __restrict__ OFh) {
  __shared__ float Ks[78][68];
  __shared__ float Vs[78][68];
  __shared__ float EXs[64][68];
  __shared__ float s0s[64];
  __shared__ float red[2];
  const int tid = threadIdx.x;
  const int w = blockIdx.x;
  const int n = blockIdx.y;
  const int f0 = w * 64;
  const int b = n >> 2, h = n & 3;

  for (int idx = tid; idx < 78 * 16; idx += 256) {
    int rr = idx >> 4, c = (idx & 15) * 4;
    int g = f0 - 7 + rr;
    float4 kv = {0.f, 0.f, 0.f, 0.f}, vv = {0.f, 0.f, 0.f, 0.f};
    if (g >= 0 && g < 4096) {
      size_t base = ((size_t)n * 4096 + g) * 64 + c;
      kv = *(const float4*)(Kb + base);
      vv = *(const float4*)(Vb + base);
    }
    *(float4*)&Ks[rr][c] = kv;
    *(float4*)&Vs[rr][c] = vv;
  }
  {
    const int wave = tid >> 6, lane = tid & 63;
    const int ln = lane & 31, half = lane >> 5;
    const int mi = wave & 1, ni = wave >> 1;
    const size_t arow = ((size_t)(b * 4096 + f0 + mi * 32 + ln)) * 64 + half * 8;
    const size_t brow =
        ((size_t)(b * 256 + h * 64 + ni * 32 + ln)) * 64 + half * 8;
    f32x16 eacc = {};
#pragma unroll
    for (int ks = 0; ks < 4; ++ks) {
      const int kc = ks * 16;
      h8 ah = *(const h8*)(wmth + arow + kc);
      h8 bh = *(const h8*)(xth + brow + kc);
      eacc = __builtin_amdgcn_mfma_f32_32x32x16_f16(ah, bh, eacc, 0, 0, 0);
    }
    const int col = ni * 32 + ln;
    const int rb2 = mi * 32 + 4 * half;
#pragma unroll
    for (int reg = 0; reg < 16; ++reg)
      EXs[rb2 + (reg & 3) + 8 * (reg >> 2)][col] = eacc[reg];
  }
  __syncthreads();

  const int i = tid >> 2, q = tid & 3;
  const int f = f0 + i;
  const size_t qbase = ((size_t)n * 4096 + f) * 64 + q * 16;
  float4 q0 = *(const float4*)(Qb + qbase);
  float4 q1 = *(const float4*)(Qb + qbase + 4);
  float4 q2 = *(const float4*)(Qb + qbase + 8);
  float4 q3 = *(const float4*)(Qb + qbase + 12);
  float4 e0 = *(const float4*)&EXs[i][q * 16];
  float4 e1 = *(const float4*)&EXs[i][q * 16 + 4];
  float4 e2 = *(const float4*)&EXs[i][q * 16 + 8];
  float4 e3 = *(const float4*)&EXs[i][q * 16 + 12];

  float s0 = q0.x * e0.x + q0.y * e0.y + q0.z * e0.z + q0.w * e0.w +
             q1.x * e1.x + q1.y * e1.y + q1.z * e1.z + q1.w * e1.w +
             q2.x * e2.x + q2.y * e2.y + q2.z * e2.z + q2.w * e2.w +
             q3.x * e3.x + q3.y * e3.y + q3.z * e3.z + q3.w * e3.w;
  s0 += __shfl_xor(s0, 1);
  s0 += __shfl_xor(s0, 2);

  float sj[15];
#pragma unroll
  for (int j = 0; j < 15; ++j) {
    const float* kr = &Ks[i + j][q * 16];
    float4 k0 = *(const float4*)(kr);
    float4 k1 = *(const float4*)(kr + 4);
    float4 k2 = *(const float4*)(kr + 8);
    float4 k3 = *(const float4*)(kr + 12);
    float s = q0.x * k0.x + q0.y * k0.y + q0.z * k0.z + q0.w * k0.w +
              q1.x * k1.x + q1.y * k1.y + q1.z * k1.z + q1.w * k1.w +
              q2.x * k2.x + q2.y * k2.y + q2.z * k2.z + q2.w * k2.w +
              q3.x * k3.x + q3.y * k3.y + q3.z * k3.z + q3.w * k3.w;
    s += __shfl_xor(s, 1);
    s += __shfl_xor(s, 2);
    sj[j] = s;
  }

  if (q == 0) s0s[i] = s0;
  __syncthreads();
  if (tid < 64) {
    float v = s0s[tid];
    float m = v;
    for (int o = 1; o < 64; o <<= 1) m = fmaxf(m, __shfl_xor(m, o));
    float ee = expf(v - m);
    float s = ee;
    for (int o = 1; o < 64; o <<= 1) s += __shfl_xor(s, o);
    if (tid == 0) { red[0] = m; red[1] = s; }
  }
  __syncthreads();
  const float wt = expf(s0 - red[0]) / red[1];

  float mx = sj[0];
#pragma unroll
  for (int j = 1; j < 15; ++j) mx = fmaxf(mx, sj[j]);
  float pj[15], den = 0.f;
#pragma unroll
  for (int j = 0; j < 15; ++j) { pj[j] = expf(sj[j] - mx); den += pj[j]; }
  const float inv = 1.0f / den;

  float o[16] = {wt * e0.x, wt * e0.y, wt * e0.z, wt * e0.w,
                 wt * e1.x, wt * e1.y, wt * e1.z, wt * e1.w,
                 wt * e2.x, wt * e2.y, wt * e2.z, wt * e2.w,
                 wt * e3.x, wt * e3.y, wt * e3.z, wt * e3.w};
#pragma unroll
  for (int j = 0; j < 15; ++j) {
    float wj = pj[j] * inv;
    const float* vr = &Vs[i + j][q * 16];
#pragma unroll
    for (int dd = 0; dd < 16; ++dd) o[dd] = fmaf(wj, vr[dd], o[dd]);
  }
  _Float16 oh[16];
#pragma unroll
  for (int dd = 0; dd < 16; ++dd) oh[dd] = (_Float16)o[dd];
  *(float4*)(OFh + qbase) = *(float4*)&oh[0];
  *(float4*)(OFh + qbase + 8) = *(float4*)&oh[8];
}

// ---------------------------------------------------------------- K3: out proj
// M=16640, N=256, K=256. Block 64x64, 4 waves (each 32x32), BK=64 x 4 iters.
__global__ __launch_bounds__(256) void out_mfma(
    const float* __restrict__ x, const _Float16* __restrict__ ofh,
    const _Float16* __restrict__ wth, const float* __restrict__ bo,
    float* __restrict__ out) {
  __shared__ _Float16 Ah[64][72], Bh[64][72];
  const int tid = threadIdx.x;
  const int wave = tid >> 6, lane = tid & 63;
  const int ln = lane & 31, half = lane >> 5;
  const int mw = (wave & 1) * 32, nw = (wave >> 1) * 32;
  const int m0 = blockIdx.x * 64, n0 = blockIdx.y * 64;
  const int sr = tid >> 2, sc4 = (tid & 3) * 16;
  const int m = m0 + sr;
  const int b = m / 4160, tt = m % 4160;
  const bool useX = (tt < 64);
  const size_t xrow = ((size_t)(b * 4160 + tt)) * 256 + sc4;  // fp32 x
  const long obase = ((long)(b * 4) * 4096 + (tt - 64)) * 64 + sc4;
  const size_t bbase = (size_t)(n0 + sr) * 256 + sc4;

  float4 ra0, ra1, rb0, rb1;
  auto OLOAD = [&](int k0_) {
    if (useX) {
      float4 fx0 = *(const float4*)(x + xrow + k0_);
      float4 fx1 = *(const float4*)(x + xrow + k0_ + 4);
      float4 fx2 = *(const float4*)(x + xrow + k0_ + 8);
      float4 fx3 = *(const float4*)(x + xrow + k0_ + 12);
      _Float16 hh[16] = {
          (_Float16)fx0.x, (_Float16)fx0.y, (_Float16)fx0.z, (_Float16)fx0.w,
          (_Float16)fx1.x, (_Float16)fx1.y, (_Float16)fx1.z, (_Float16)fx1.w,
          (_Float16)fx2.x, (_Float16)fx2.y, (_Float16)fx2.z, (_Float16)fx2.w,
          (_Float16)fx3.x, (_Float16)fx3.y, (_Float16)fx3.z, (_Float16)fx3.w};
      ra0 = *(float4*)&hh[0];
      ra1 = *(float4*)&hh[8];
    } else {
      size_t o_ = (size_t)(obase + (long)(k0_ >> 6) * 262144);
      ra0 = *(const float4*)(ofh + o_);
      ra1 = *(const float4*)(ofh + o_ + 8);
    }
    rb0 = *(const float4*)(wth + bbase + k0_);
    rb1 = *(const float4*)(wth + bbase + k0_ + 8);
  };

  OLOAD(0);
  f32x16 acc = {};
  for (int it = 0; it < 4; ++it) {
    __syncthreads();
    *(float4*)&Ah[sr][sc4] = ra0;
    *(float4*)&Ah[sr][sc4 + 8] = ra1;
    *(float4*)&Bh[sr][sc4] = rb0;
    *(float4*)&Bh[sr][sc4 + 8] = rb1;
    __syncthreads();
    if (it < 3) OLOAD((it + 1) * 64);
#pragma unroll
    for (int ks = 0; ks < 4; ++ks) {
      const int kc = ks * 16 + half * 8;
      h8 ah = *(const h8*)&Ah[mw + ln][kc];
      h8 bh = *(const h8*)&Bh[nw + ln][kc];
      acc = __builtin_amdgcn_mfma_f32_32x32x16_f16(ah, bh, acc, 0, 0, 0);
    }
  }
  const int c = n0 + nw + ln;
  const float bias = bo[c];
  const int rb = m0 + mw + 4 * half;
#pragma unroll
  for (int reg = 0; reg < 16; ++reg) {
    int rr = rb + (reg & 3) + 8 * (reg >> 2);
    out[(size_t)rr * 256 + c] = acc[reg] + bias;
  }
}

// ---------------------------------------------------------------- launch
extern "C" void kernel_launch(void* const* d_in, const int* in_sizes, int n_in,
                              void* d_out, int out_size, void* d_ws, size_t ws_size,
                              hipStream_t stream) {
  const float* x  = (const float*)d_in[0];
  const float* wm = (const float*)d_in[1];
  const float* Wq = (const float*)d_in[2];
  const float* bq = (const float*)d_in[3];
  const float* Wo = (const float*)d_in[4];
  const float* bo = (const float*)d_in[5];
  float* out = (float*)d_out;
  float* ws = (float*)d_ws;

  float* Qb = ws;
  float* Kb = Qb + QN;
  float* Vb = Kb + QN;
  _Float16* OFh  = (_Float16*)(Vb + QN);
  _Float16* Woth = OFh + QN;        // [256][256]
  _Float16* wmTh = Woth + 65536;    // [4][4096][64]
  _Float16* xTh  = wmTh + 1048576;  // [4][256][64]
  // total ~61 MB of workspace

  qkv_conv<<<dim3(1284), 256, 0, stream>>>(x, wm, Wq, Wo, bq, Qb, Kb, Vb,
                                           Woth, wmTh, xTh);
  attn_fused<<<dim3(64, 16), 256, 0, stream>>>(Qb, Kb, Vb, wmTh, xTh, OFh);
  out_mfma<<<dim3(260, 4), 256, 0, stream>>>(x, OFh, Woth, bo, out);
}

// Round 12
// 127.402 us; speedup vs baseline: 1.0186x; 1.0186x over previous
//
#include <hip/hip_runtime.h>

// Speech MSA with dynamic windows.
// B=4, T=4160 (W=64 word tokens + F=4096 frames), E=256, H=4, D=64,
// LOCAL_SIZE=15 (pad 7), chunk = F/W = 64, n = B*H = 16.
//
// R12: R10 structure (best measured: 127.4 us, 4 dispatches) with Q/K/V
// intermediates stored as f16 (halves qkv epilogue writes + attn reads;
// scores/softmax/PV still fp32 — K/V cvt to fp32 during LDS staging).
// Error model: +~1e-3 softmax-weight shift, expect absmax ~0.010-0.016
// vs threshold 2.66e-2. R11's inline-Wq variant reverted (neutral-negative).

#define QN 4194304ull  // 16 * 4096 * 64 elements (head-layout buffers)

typedef _Float16 h8 __attribute__((ext_vector_type(8)));
typedef _Float16 h4 __attribute__((ext_vector_type(4)));
typedef float f32x16 __attribute__((ext_vector_type(16)));

// ------------------------------------------------- small conversion kernel
// g [0,768):     WqT [768][256] f16
// g [768,1024):  WoT [256][256] f16
// g [1024,1280): wmT [b][f][w]  f16 (LDS 64x64 tile transpose)
// g [1280,1284): xT  [b][c][w]  f16 (word-token rows transposed)
__global__ __launch_bounds__(256) void conv_small(
    const float* __restrict__ x, const float* __restrict__ wm,
    const float* __restrict__ Wq, const float* __restrict__ Wo,
    _Float16* __restrict__ wqth, _Float16* __restrict__ woth,
    _Float16* __restrict__ wmth, _Float16* __restrict__ xth) {
  __shared__ float S[64 * 65];
  const int g = blockIdx.x, tid = threadIdx.x;
  if (g < 768) {
    int o = g * 256 + tid;
    int n = o >> 8, k = o & 255;
    wqth[o] = (_Float16)Wq[(size_t)k * 768 + n];
  } else if (g < 1024) {
    int o = (g - 768) * 256 + tid;
    int n = o >> 8, k = o & 255;
    woth[o] = (_Float16)Wo[(size_t)k * 256 + n];
  } else if (g < 1280) {
    int local = g - 1024;
    int b = local >> 6, f0 = (local & 63) * 64;
    {
      int w = tid >> 2, c0 = (tid & 3) * 16;
      const float* src = wm + ((size_t)(b * 64 + w)) * 4096 + f0 + c0;
#pragma unroll
      for (int cc = 0; cc < 16; cc += 4)
        *(float4*)&S[w * 65 + c0 + cc] = *(const float4*)(src + cc);
    }
    __syncthreads();
    {
      int fl = tid >> 2, w0 = (tid & 3) * 16;
      int f = f0 + fl;
      _Float16 hh[16];
#pragma unroll
      for (int j = 0; j < 16; ++j) hh[j] = (_Float16)S[(w0 + j) * 65 + fl];
      size_t o = ((size_t)b * 4096 + f) * 64 + w0;
      *(float4*)(wmth + o) = *(float4*)&hh[0];
      *(float4*)(wmth + o + 8) = *(float4*)&hh[8];
    }
  } else {
    int b = g - 1280;
    for (int c0 = 0; c0 < 256; c0 += 64) {
      __syncthreads();
      {
        int w = tid >> 2, cl0 = (tid & 3) * 16;
        const float* src = x + ((size_t)(b * 4160 + w)) * 256 + c0 + cl0;
#pragma unroll
        for (int cc = 0; cc < 16; cc += 4)
          *(float4*)&S[w * 65 + cl0 + cc] = *(const float4*)(src + cc);
      }
      __syncthreads();
      {
        int cl = tid >> 2, w0 = (tid & 3) * 16;
        _Float16 hh[16];
#pragma unroll
        for (int j = 0; j < 16; ++j) hh[j] = (_Float16)S[(w0 + j) * 65 + cl];
        size_t o = ((size_t)(b * 256 + c0 + cl)) * 64 + w0;
        *(float4*)(xth + o) = *(float4*)&hh[0];
        *(float4*)(xth + o + 8) = *(float4*)&hh[8];
      }
    }
  }
}

// ---------------------------------------------------------------- K1: QKV gemm
// M=16384, N=768, K=256. Block 128x128, 4 waves (each 64x64), BK=32 x 8 iters.
// Epilogue writes f16 Q/K/V (bias+scale in fp32, then cvt).
__global__ __launch_bounds__(256) void qkv_mfma(
    const float* __restrict__ x, const _Float16* __restrict__ wth,
    const float* __restrict__ bq,
    _Float16* __restrict__ Qh, _Float16* __restrict__ Kh,
    _Float16* __restrict__ Vh) {
  __shared__ _Float16 Ah[128][40], Bh[128][40];
  const int tid = threadIdx.x;
  const int wave = tid >> 6, lane = tid & 63;
  const int ln = lane & 31, half = lane >> 5;
  const int mw = (wave & 1) * 64, nw = (wave >> 1) * 64;
  const int m0 = blockIdx.x * 128, n0 = blockIdx.y * 128;

  const int sr = tid >> 1, scq = (tid & 1) * 16;
  const int am = m0 + sr;
  const size_t arow =
      ((size_t)((am >> 12) * 4160 + 64 + (am & 4095))) * 256 + scq;
  const size_t brow = (size_t)(n0 + sr) * 256 + scq;

  float4 rah0, rah1, rbh0, rbh1;
  auto QLOAD = [&](int k0_) {
    float4 fx0 = *(const float4*)(x + arow + k0_);
    float4 fx1 = *(const float4*)(x + arow + k0_ + 4);
    float4 fx2 = *(const float4*)(x + arow + k0_ + 8);
    float4 fx3 = *(const float4*)(x + arow + k0_ + 12);
    rbh0 = *(const float4*)(wth + brow + k0_);
    rbh1 = *(const float4*)(wth + brow + k0_ + 8);
    _Float16 hh[16] = {
        (_Float16)fx0.x, (_Float16)fx0.y, (_Float16)fx0.z, (_Float16)fx0.w,
        (_Float16)fx1.x, (_Float16)fx1.y, (_Float16)fx1.z, (_Float16)fx1.w,
        (_Float16)fx2.x, (_Float16)fx2.y, (_Float16)fx2.z, (_Float16)fx2.w,
        (_Float16)fx3.x, (_Float16)fx3.y, (_Float16)fx3.z, (_Float16)fx3.w};
    rah0 = *(float4*)&hh[0];
    rah1 = *(float4*)&hh[8];
  };

  QLOAD(0);
  f32x16 acc[2][2] = {};

  for (int it = 0; it < 8; ++it) {
    __syncthreads();
    *(float4*)&Ah[sr][scq] = rah0;
    *(float4*)&Ah[sr][scq + 8] = rah1;
    *(float4*)&Bh[sr][scq] = rbh0;
    *(float4*)&Bh[sr][scq + 8] = rbh1;
    __syncthreads();
    if (it < 7) QLOAD((it + 1) * 32);
#pragma unroll
    for (int ks = 0; ks < 2; ++ks) {
      const int kc = ks * 16 + half * 8;
      h8 a0 = *(const h8*)&Ah[mw + ln][kc];
      h8 a1 = *(const h8*)&Ah[mw + 32 + ln][kc];
      h8 b0 = *(const h8*)&Bh[nw + ln][kc];
      h8 b1 = *(const h8*)&Bh[nw + 32 + ln][kc];
      acc[0][0] = __builtin_amdgcn_mfma_f32_32x32x16_f16(a0, b0, acc[0][0], 0, 0, 0);
      acc[0][1] = __builtin_amdgcn_mfma_f32_32x32x16_f16(a0, b1, acc[0][1], 0, 0, 0);
      acc[1][0] = __builtin_amdgcn_mfma_f32_32x32x16_f16(a1, b0, acc[1][0], 0, 0, 0);
      acc[1][1] = __builtin_amdgcn_mfma_f32_32x32x16_f16(a1, b1, acc[1][1], 0, 0, 0);
    }
  }

  // C/D: col = ln, row = (reg&3) + 8*(reg>>2) + 4*half
#pragma unroll
  for (int ni = 0; ni < 2; ++ni) {
    const int c = n0 + nw + ni * 32 + ln;
    const int which = c >> 8, e = c & 255;
    const int h = e >> 6, d = e & 63;
    _Float16* dst = (which == 0) ? Qh : (which == 1) ? Kh : Vh;
    const float sc2 = (which == 0) ? 0.125f : 1.0f;
    const float bias = bq[c];
#pragma unroll
    for (int mi = 0; mi < 2; ++mi) {
      const int rb = m0 + mw + mi * 32 + 4 * half;
#pragma unroll
      for (int reg = 0; reg < 16; ++reg) {
        int rr = rb + (reg & 3) + 8 * (reg >> 2);
        int b2 = rr >> 12, f2 = rr & 4095;
        dst[(((size_t)(b2 * 4 + h)) * 4096 + f2) * 64 + d] =
            (_Float16)((acc[mi][ni][reg] + bias) * sc2);
      }
    }
  }
}

// ------------------------------------------------- K2: fused expa + attention
// Q/K/V read as f16, converted to fp32 at staging; all math fp32 as before.
__global__ __launch_bounds__(256) void attn_fused(
    const _Float16* __restrict__ Qh, const _Float16* __restrict__ Kh,
    const _Float16* __restrict__ Vh,
    const _Float16* __restrict__ wmth, const _Float16* __restrict__ xth,
    _Float16* __restrict__ OFh) {
  __shared__ float Ks[78][68];
  __shared__ float Vs[78][68];
  __shared__ float EXs[64][68];
  __shared__ float s0s[64];
  __shared__ float red[2];
  const int tid = threadIdx.x;
  const int w = blockIdx.x;
  const int n = blockIdx.y;
  const int f0 = w * 64;
  const int b = n >> 2, h = n & 3;

  for (int idx = tid; idx < 78 * 16; idx += 256) {
    int rr = idx >> 4, c = (idx & 15) * 4;
    int g = f0 - 7 + rr;
    float4 kv = {0.f, 0.f, 0.f, 0.f}, vv = {0.f, 0.f, 0.f, 0.f};
    if (g >= 0 && g < 4096) {
      size_t base = ((size_t)n * 4096 + g) * 64 + c;
      h4 k4 = *(const h4*)(Kh + base);
      h4 v4 = *(const h4*)(Vh + base);
      kv = {(float)k4.x, (float)k4.y, (float)k4.z, (float)k4.w};
      vv = {(float)v4.x, (float)v4.y, (float)v4.z, (float)v4.w};
    }
    *(float4*)&Ks[rr][c] = kv;
    *(float4*)&Vs[rr][c] = vv;
  }
  {
    const int wave = tid >> 6, lane = tid & 63;
    const int ln = lane & 31, half = lane >> 5;
    const int mi = wave & 1, ni = wave >> 1;
    const size_t arow = ((size_t)(b * 4096 + f0 + mi * 32 + ln)) * 64 + half * 8;
    const size_t brow =
        ((size_t)(b * 256 + h * 64 + ni * 32 + ln)) * 64 + half * 8;
    f32x16 eacc = {};
#pragma unroll
    for (int ks = 0; ks < 4; ++ks) {
      const int kc = ks * 16;
      h8 ah = *(const h8*)(wmth + arow + kc);
      h8 bh = *(const h8*)(xth + brow + kc);
      eacc = __builtin_amdgcn_mfma_f32_32x32x16_f16(ah, bh, eacc, 0, 0, 0);
    }
    const int col = ni * 32 + ln;
    const int rb2 = mi * 32 + 4 * half;
#pragma unroll
    for (int reg = 0; reg < 16; ++reg)
      EXs[rb2 + (reg & 3) + 8 * (reg >> 2)][col] = eacc[reg];
  }
  __syncthreads();

  const int i = tid >> 2, q = tid & 3;
  const int f = f0 + i;
  const size_t qbase = ((size_t)n * 4096 + f) * 64 + q * 16;
  h8 qh0 = *(const h8*)(Qh + qbase);
  h8 qh1 = *(const h8*)(Qh + qbase + 8);
  float4 q0 = {(float)qh0.s0, (float)qh0.s1, (float)qh0.s2, (float)qh0.s3};
  float4 q1 = {(float)qh0.s4, (float)qh0.s5, (float)qh0.s6, (float)qh0.s7};
  float4 q2 = {(float)qh1.s0, (float)qh1.s1, (float)qh1.s2, (float)qh1.s3};
  float4 q3 = {(float)qh1.s4, (float)qh1.s5, (float)qh1.s6, (float)qh1.s7};
  float4 e0 = *(const float4*)&EXs[i][q * 16];
  float4 e1 = *(const float4*)&EXs[i][q * 16 + 4];
  float4 e2 = *(const float4*)&EXs[i][q * 16 + 8];
  float4 e3 = *(const float4*)&EXs[i][q * 16 + 12];

  float s0 = q0.x * e0.x + q0.y * e0.y + q0.z * e0.z + q0.w * e0.w +
             q1.x * e1.x + q1.y * e1.y + q1.z * e1.z + q1.w * e1.w +
             q2.x * e2.x + q2.y * e2.y + q2.z * e2.z + q2.w * e2.w +
             q3.x * e3.x + q3.y * e3.y + q3.z * e3.z + q3.w * e3.w;
  s0 += __shfl_xor(s0, 1);
  s0 += __shfl_xor(s0, 2);

  float sj[15];
#pragma unroll
  for (int j = 0; j < 15; ++j) {
    const float* kr = &Ks[i + j][q * 16];
    float4 k0 = *(const float4*)(kr);
    float4 k1 = *(const float4*)(kr + 4);
    float4 k2 = *(const float4*)(kr + 8);
    float4 k3 = *(const float4*)(kr + 12);
    float s = q0.x * k0.x + q0.y * k0.y + q0.z * k0.z + q0.w * k0.w +
              q1.x * k1.x + q1.y * k1.y + q1.z * k1.z + q1.w * k1.w +
              q2.x * k2.x + q2.y * k2.y + q2.z * k2.z + q2.w * k2.w +
              q3.x * k3.x + q3.y * k3.y + q3.z * k3.z + q3.w * k3.w;
    s += __shfl_xor(s, 1);
    s += __shfl_xor(s, 2);
    sj[j] = s;
  }

  if (q == 0) s0s[i] = s0;
  __syncthreads();
  if (tid < 64) {
    float v = s0s[tid];
    float m = v;
    for (int o = 1; o < 64; o <<= 1) m = fmaxf(m, __shfl_xor(m, o));
    float ee = expf(v - m);
    float s = ee;
    for (int o = 1; o < 64; o <<= 1) s += __shfl_xor(s, o);
    if (tid == 0) { red[0] = m; red[1] = s; }
  }
  __syncthreads();
  const float wt = expf(s0 - red[0]) / red[1];

  float mx = sj[0];
#pragma unroll
  for (int j = 1; j < 15; ++j) mx = fmaxf(mx, sj[j]);
  float pj[15], den = 0.f;
#pragma unroll
  for (int j = 0; j < 15; ++j) { pj[j] = expf(sj[j] - mx); den += pj[j]; }
  const float inv = 1.0f / den;

  float o[16] = {wt * e0.x, wt * e0.y, wt * e0.z, wt * e0.w,
                 wt * e1.x, wt * e1.y, wt * e1.z, wt * e1.w,
                 wt * e2.x, wt * e2.y, wt * e2.z, wt * e2.w,
                 wt * e3.x, wt * e3.y, wt * e3.z, wt * e3.w};
#pragma unroll
  for (int j = 0; j < 15; ++j) {
    float wj = pj[j] * inv;
    const float* vr = &Vs[i + j][q * 16];
#pragma unroll
    for (int dd = 0; dd < 16; ++dd) o[dd] = fmaf(wj, vr[dd], o[dd]);
  }
  _Float16 oh[16];
#pragma unroll
  for (int dd = 0; dd < 16; ++dd) oh[dd] = (_Float16)o[dd];
  *(float4*)(OFh + qbase) = *(float4*)&oh[0];
  *(float4*)(OFh + qbase + 8) = *(float4*)&oh[8];
}

// ---------------------------------------------------------------- K3: out proj
// M=16640, N=256, K=256. Block 64x64, 4 waves (each 32x32), BK=64 x 4 iters.
__global__ __launch_bounds__(256) void out_mfma(
    const float* __restrict__ x, const _Float16* __restrict__ ofh,
    const _Float16* __restrict__ wth, const float* __restrict__ bo,
    float* __restrict__ out) {
  __shared__ _Float16 Ah[64][72], Bh[64][72];
  const int tid = threadIdx.x;
  const int wave = tid >> 6, lane = tid & 63;
  const int ln = lane & 31, half = lane >> 5;
  const int mw = (wave & 1) * 32, nw = (wave >> 1) * 32;
  const int m0 = blockIdx.x * 64, n0 = blockIdx.y * 64;
  const int sr = tid >> 2, sc4 = (tid & 3) * 16;
  const int m = m0 + sr;
  const int b = m / 4160, tt = m % 4160;
  const bool useX = (tt < 64);
  const size_t xrow = ((size_t)(b * 4160 + tt)) * 256 + sc4;  // fp32 x
  const long obase = ((long)(b * 4) * 4096 + (tt - 64)) * 64 + sc4;
  const size_t bbase = (size_t)(n0 + sr) * 256 + sc4;

  float4 ra0, ra1, rb0, rb1;
  auto OLOAD = [&](int k0_) {
    if (useX) {
      float4 fx0 = *(const float4*)(x + xrow + k0_);
      float4 fx1 = *(const float4*)(x + xrow + k0_ + 4);
      float4 fx2 = *(const float4*)(x + xrow + k0_ + 8);
      float4 fx3 = *(const float4*)(x + xrow + k0_ + 12);
      _Float16 hh[16] = {
          (_Float16)fx0.x, (_Float16)fx0.y, (_Float16)fx0.z, (_Float16)fx0.w,
          (_Float16)fx1.x, (_Float16)fx1.y, (_Float16)fx1.z, (_Float16)fx1.w,
          (_Float16)fx2.x, (_Float16)fx2.y, (_Float16)fx2.z, (_Float16)fx2.w,
          (_Float16)fx3.x, (_Float16)fx3.y, (_Float16)fx3.z, (_Float16)fx3.w};
      ra0 = *(float4*)&hh[0];
      ra1 = *(float4*)&hh[8];
    } else {
      size_t o_ = (size_t)(obase + (long)(k0_ >> 6) * 262144);
      ra0 = *(const float4*)(ofh + o_);
      ra1 = *(const float4*)(ofh + o_ + 8);
    }
    rb0 = *(const float4*)(wth + bbase + k0_);
    rb1 = *(const float4*)(wth + bbase + k0_ + 8);
  };

  OLOAD(0);
  f32x16 acc = {};
  for (int it = 0; it < 4; ++it) {
    __syncthreads();
    *(float4*)&Ah[sr][sc4] = ra0;
    *(float4*)&Ah[sr][sc4 + 8] = ra1;
    *(float4*)&Bh[sr][sc4] = rb0;
    *(float4*)&Bh[sr][sc4 + 8] = rb1;
    __syncthreads();
    if (it < 3) OLOAD((it + 1) * 64);
#pragma unroll
    for (int ks = 0; ks < 4; ++ks) {
      const int kc = ks * 16 + half * 8;
      h8 ah = *(const h8*)&Ah[mw + ln][kc];
      h8 bh = *(const h8*)&Bh[nw + ln][kc];
      acc = __builtin_amdgcn_mfma_f32_32x32x16_f16(ah, bh, acc, 0, 0, 0);
    }
  }
  const int c = n0 + nw + ln;
  const float bias = bo[c];
  const int rb = m0 + mw + 4 * half;
#pragma unroll
  for (int reg = 0; reg < 16; ++reg) {
    int rr = rb + (reg & 3) + 8 * (reg >> 2);
    out[(size_t)rr * 256 + c] = acc[reg] + bias;
  }
}

// ---------------------------------------------------------------- launch
extern "C" void kernel_launch(void* const* d_in, const int* in_sizes, int n_in,
                              void* d_out, int out_size, void* d_ws, size_t ws_size,
                              hipStream_t stream) {
  const float* x  = (const float*)d_in[0];
  const float* wm = (const float*)d_in[1];
  const float* Wq = (const float*)d_in[2];
  const float* bq = (const float*)d_in[3];
  const float* Wo = (const float*)d_in[4];
  const float* bo = (const float*)d_in[5];
  float* out = (float*)d_out;

  _Float16* Qh   = (_Float16*)d_ws;  // f16 head-layout, QN each
  _Float16* Kh   = Qh + QN;
  _Float16* Vh   = Kh + QN;
  _Float16* OFh  = Vh + QN;
  _Float16* Wqth = OFh + QN;        // [768][256]
  _Float16* Woth = Wqth + 196608;   // [256][256]
  _Float16* wmTh = Woth + 65536;    // [4][4096][64]
  _Float16* xTh  = wmTh + 1048576;  // [4][256][64]
  // total ~36 MB of workspace

  conv_small<<<dim3(1284), 256, 0, stream>>>(x, wm, Wq, Wo, Wqth, Woth, wmTh,
                                             xTh);
  qkv_mfma<<<dim3(128, 6), 256, 0, stream>>>(x, Wqth, bq, Qh, Kh, Vh);
  attn_fused<<<dim3(64, 16), 256, 0, stream>>>(Qh, Kh, Vh, wmTh, xTh, OFh);
  out_mfma<<<dim3(260, 4), 256, 0, stream>>>(x, OFh, Woth, bo, out);
}